// Round 5
// baseline (938.997 us; speedup 1.0000x reference)
//
#include <hip/hip_runtime.h>
#include <math.h>

typedef __attribute__((ext_vector_type(4))) float f4;
typedef __attribute__((ext_vector_type(8))) _Float16 f16x8;
typedef __attribute__((ext_vector_type(4))) unsigned short u16x4;
typedef unsigned int u32;
typedef unsigned short u16;

#define DIMC  512
#define NITEM 2048
#define TK    10
#define WSP   (NITEM * DIMC)        // ws plane stride (u16 elems)

// ---------------- main kernel geometry ----------------
#define TPB    512                  // 8 waves
#define PXB    64                   // pixels per block
#define RIT    256                  // items per round
#define NRND   8
#define NSLICE 16                   // K-slices of 32 (K=512)
#define SCL    4.8828125e-4f        // 2^-11 (residual-plane scale)

// ---------------- LDS layout (bytes) ----------------
//   mp double-buffer: buf b at b*32768, plane p at +p*16384  [0..65536)
//   q  double-buffer: Q_BASE + b*8192, plane p at +p*4096    [65536..81920)
//   S overlay [256][66] f32 at 0..67583 (staging dead when used)
//   merge arrays overlay S low region
#define MP_BUF 32768
#define MP_PL  16384
#define Q_BASE 65536
#define Q_BUF  8192
#define Q_PL   4096
#define SSTR   66
#define LDS_BYTES 81920  // 80 KB -> 2 blocks/CU (exactly 160 KB)
// merge overlay (float indices from base 0)
#define MV_F 0        // [64][8][10] vals
#define MI_F 5120     // [64][8][10] idx
#define MM_F 10240    // [64][8] max
#define MS_F 10752    // [64][8] sum
#define WB_F 11264    // [64][10] weights
#define IB_F 11904    // [64][10] indices

// bank-spread swizzle key for 16-row fragment tiles (2-way residual = free)
#define KSWZ(i) (((i) ^ ((i) >> 2)) & 3)

union h16 { _Float16 h; u16 u; };

// fp16 dual-plane split: f ~= lo + 2^-11 * hi  (hi = fp16((f-lo)*2^11))
__device__ __forceinline__ void split2(float f, u16& lo, u16& hi) {
    h16 a; a.h = (_Float16)f;
    float f0 = (float)a.h;
    h16 b; b.h = (_Float16)((f - f0) * 2048.0f);
    lo = a.u; hi = b.u;
}

// mempool fp32 -> 2 fp16 planes in ws, k stored in MFMA fragment permutation:
// within each 32-k slice, position = ((kl>>2)&3)*8 + (kl>>4)*4 + (kl&3)
// (identical perm for A and B -> correctness-invariant to HW k-grouping).
__global__ __launch_bounds__(256)
void preconv_kernel(const float* __restrict__ mp, u16* __restrict__ ws)
{
    int idx = (blockIdx.x * 256 + threadIdx.x) * 4;   // 1024 blocks -> exact
    int i  = idx >> 9;
    int k0 = idx & 511;
    f4 v = *(const f4*)(mp + (size_t)i * 512 + k0);
    int s  = k0 >> 5, kl = k0 & 31;
    int pos = s * 32 + ((kl >> 2) & 3) * 8 + (kl >> 4) * 4;  // + e (e=0..3)
    u16x4 p0, p1;
#pragma unroll
    for (int e = 0; e < 4; ++e) {
        u16 lo, hi; split2(v[e], lo, hi);
        p0[e] = lo; p1[e] = hi;
    }
    size_t base = (size_t)i * 512 + pos;
    *(u16x4*)(ws + 0 * WSP + base) = p0;
    *(u16x4*)(ws + 1 * WSP + base) = p1;
}

__global__ __launch_bounds__(TPB, 4)
void memorize_mfma(const float* __restrict__ x0, const float* __restrict__ x1,
                   const float* __restrict__ mp, const u16* __restrict__ ws,
                   float* __restrict__ out)
{
    extern __shared__ char ldsb[];
    float* ldsf = (float*)ldsb;

    const int t    = threadIdx.x;
    const int lane = t & 63;
    const int w    = t >> 6;            // wave 0..7
    const int blk  = blockIdx.x;        // 0..511
    const int img  = blk >> 4;          // 0..31
    const int n0   = (blk & 15) * PXB;  // pixel base (HW = 1024)
    const int b    = img & 15;

    const float* x  = (img < 16) ? x0 : x1;
    const float* xb = x + (size_t)b * (DIMC * 1024);
    float* ob = out + (img < 16 ? (size_t)0 : (size_t)16 * DIMC * 1024)
                    + (size_t)b * (DIMC * 1024);

    const int l15 = lane & 15;
    const int lh  = lane >> 4;          // fragment h-group 0..3
    const int ksw = lh ^ KSWZ(l15);     // swizzled 16B slot for frag reads

    // scan mapping: 8 groups of 32 items per round per pixel
    const int qp = t & 63;
    const int g  = t >> 6;

    float tv[TK]; int tix[TK];
#pragma unroll
    for (int q = 0; q < TK; ++q) { tv[q] = -INFINITY; tix[q] = 0x7fffffff; }
    float rm = -INFINITY, rs = 0.0f;

    // q staging mapping: thread -> (k-local scl, 4 px)
    const int scl  = t & 31;
    const int spx  = (t >> 5) << 2;     // 0..60
    const int spos = (((scl >> 2) & 3) << 3) + ((scl >> 4) << 2) + (scl & 3);
    const int sslot = spos >> 3;        // true 16B k-slot of this write
    const int soff  = (spos & 7) << 1;  // byte offset within slot

    // mp staging: per-lane source k-slot pre-swizzle (LDS dest stays linear)
    const int itq = lane >> 2;                 // item-local within 16-group
    const int slo = lane & 3;                  // LDS 16B slot this lane fills
    const int ksrc = slo ^ KSWZ(itq);          // true k-slot to fetch

    // staging helpers -----------------------------------------------------
#define STAGE_MP(R, S, BUF)                                                    \
    {                                                                          \
        _Pragma("unroll")                                                      \
        for (int p = 0; p < 2; ++p) {                                          \
            _Pragma("unroll")                                                  \
            for (int qg = 0; qg < 2; ++qg) {                                   \
                int I = (w << 5) + (qg << 4);                                  \
                const u16* src = ws + (size_t)p * WSP                          \
                               + (size_t)((R) * RIT + I + itq) * 512           \
                               + ((S) << 5) + (ksrc << 3);                     \
                char* dst = ldsb + (BUF) * MP_BUF + p * MP_PL + I * 64;        \
                __builtin_amdgcn_global_load_lds(                              \
                    (const __attribute__((address_space(1))) u32*)src,         \
                    (__attribute__((address_space(3))) u32*)dst, 16, 0, 0);    \
            }                                                                  \
        }                                                                      \
    }

#define STAGE_Q(S, BUF)                                                        \
    {                                                                          \
        const float* src = xb + (size_t)(((S) << 5) + scl) * 1024 + n0 + spx;  \
        f4 v = *(const f4*)src;                                                \
        _Pragma("unroll")                                                      \
        for (int e = 0; e < 4; ++e) {                                          \
            int px = spx + e;                                                  \
            u16 lo, hi; split2(v[e], lo, hi);                                  \
            int ro = Q_BASE + (BUF) * Q_BUF + (px << 6)                        \
                   + (((sslot ^ KSWZ(px)) << 4) | soff);                       \
            *(u16*)(ldsb + ro)        = lo;                                    \
            *(u16*)(ldsb + ro + Q_PL) = hi;                                    \
        }                                                                      \
    }

#pragma unroll 1
    for (int r = 0; r < NRND; ++r) {
        f4 acc0[2][4], acc1[2][4];
#pragma unroll
        for (int mt = 0; mt < 2; ++mt)
#pragma unroll
            for (int nt = 0; nt < 4; ++nt) {
                acc0[mt][nt] = (f4){0.f, 0.f, 0.f, 0.f};
                acc1[mt][nt] = (f4){0.f, 0.f, 0.f, 0.f};
            }

        // cold start: stage slice 0 into buf 0
        __syncthreads();            // prev round's scan reads done (S dead)
        STAGE_MP(r, 0, 0)
        STAGE_Q(0, 0)
        __syncthreads();

#pragma unroll 2
        for (int s = 0; s < NSLICE; ++s) {
            const int cur = s & 1;
            // prefetch next slice into the other buffer (overlaps MFMAs)
            if (s < NSLICE - 1) {
                STAGE_MP(r, s + 1, cur ^ 1)
                STAGE_Q(s + 1, cur ^ 1)
            }

            // fragment reads from current buffers
            const char* qbc = ldsb + Q_BASE + cur * Q_BUF + (l15 << 6) + (ksw << 4);
            const char* abc = ldsb + cur * MP_BUF + (size_t)((w << 5) + l15) * 64 + (ksw << 4);

            f16x8 bq[4][2];
#pragma unroll
            for (int nt = 0; nt < 4; ++nt)
#pragma unroll
                for (int p = 0; p < 2; ++p)
                    bq[nt][p] = *(const f16x8*)(qbc + p * Q_PL + nt * 1024);

#pragma unroll
            for (int mt = 0; mt < 2; ++mt) {
                f16x8 a0 = *(const f16x8*)(abc + 0 * MP_PL + mt * 1024);
                f16x8 a1 = *(const f16x8*)(abc + 1 * MP_PL + mt * 1024);
#pragma unroll
                for (int nt = 0; nt < 4; ++nt) {
                    acc0[mt][nt] = __builtin_amdgcn_mfma_f32_16x16x32_f16(
                        a0, bq[nt][0], acc0[mt][nt], 0, 0, 0);
                    acc1[mt][nt] = __builtin_amdgcn_mfma_f32_16x16x32_f16(
                        a0, bq[nt][1], acc1[mt][nt], 0, 0, 0);
                    acc1[mt][nt] = __builtin_amdgcn_mfma_f32_16x16x32_f16(
                        a1, bq[nt][0], acc1[mt][nt], 0, 0, 0);
                }
            }
            __syncthreads();        // next-slice staging complete; frag reads done
        }

        // ---- drain accs to S overlay: row=item-local, col=px ----
#pragma unroll
        for (int mt = 0; mt < 2; ++mt) {
#pragma unroll
            for (int nt = 0; nt < 4; ++nt) {
                int row = (w << 5) + (mt << 4) + (lh << 2);   // + reg
                int col = (nt << 4) + l15;
                float* sp = ldsf + row * SSTR + col;
                sp[0 * SSTR] = acc0[mt][nt][0] + SCL * acc1[mt][nt][0];
                sp[1 * SSTR] = acc0[mt][nt][1] + SCL * acc1[mt][nt][1];
                sp[2 * SSTR] = acc0[mt][nt][2] + SCL * acc1[mt][nt][2];
                sp[3 * SSTR] = acc0[mt][nt][3] + SCL * acc1[mt][nt][3];
            }
        }
        __syncthreads();

        // ---- scan sweep 1: max + guarded top-10 insert (32 items/thread) ----
        float mloc = rm;
#pragma unroll 4
        for (int jj = 0; jj < 32; ++jj) {
            int   il = (g << 5) + jj;
            float v  = ldsf[il * SSTR + qp];
            mloc = fmaxf(mloc, v);
            if (v > tv[TK - 1]) {
                int   id = r * RIT + il;
                float cv = v; int ci = id;
#pragma unroll
                for (int q = 0; q < TK; ++q) {
                    bool  gt = cv > tv[q];
                    float nv = gt ? tv[q]  : cv;
                    int   ni = gt ? tix[q] : ci;
                    tv[q]  = gt ? cv : tv[q];
                    tix[q] = gt ? ci : tix[q];
                    cv = nv; ci = ni;
                }
            }
        }
        rs *= __expf(rm - mloc);   // round 0: rs==0 -> ok
        rm = mloc;
        // ---- scan sweep 2: exp-sum at fixed max ----
#pragma unroll 4
        for (int jj = 0; jj < 32; ++jj) {
            int   il = (g << 5) + jj;
            float v  = ldsf[il * SSTR + qp];
            rs += __expf(v - rm);
        }
    }

    // ---- dump per-thread partials for merge ----
    __syncthreads();
    {
#pragma unroll
        for (int q = 0; q < TK; ++q) {
            ldsf[MV_F + (qp * 8 + g) * TK + q] = tv[q];
            ldsf[MI_F + (qp * 8 + g) * TK + q] = __int_as_float(tix[q]);
        }
        ldsf[MM_F + qp * 8 + g] = rm;
        ldsf[MS_F + qp * 8 + g] = rs;
    }
    __syncthreads();

    // ---- merge 8 partial lists per pixel; double softmax ----
    if (t < 64) {
        const int p = t;
        float gm[8], gs[8];
#pragma unroll
        for (int G = 0; G < 8; ++G) {
            gm[G] = ldsf[MM_F + p * 8 + G];
            gs[G] = ldsf[MS_F + p * 8 + G];
        }
        float mstar = gm[0];
#pragma unroll
        for (int G = 1; G < 8; ++G) mstar = fmaxf(mstar, gm[G]);
        float Z = 0.0f;
#pragma unroll
        for (int G = 0; G < 8; ++G) Z += gs[G] * __expf(gm[G] - mstar);

        int h0=0,h1=0,h2=0,h3=0,h4=0,h5=0,h6=0,h7=0;
        float ov[TK]; int oi[TK];
#pragma unroll
        for (int o = 0; o < TK; ++o) {
            float bv = -INFINITY; int bi = 0x7fffffff; int bg = 0;
#define SEL(G, HG)                                                               \
            {                                                                    \
                float v  = ldsf[MV_F + (p * 8 + G) * TK + (HG)];                 \
                int   id = __float_as_int(ldsf[MI_F + (p * 8 + G) * TK + (HG)]); \
                if (v > bv || (v == bv && id < bi)) { bv = v; bi = id; bg = G; } \
            }
            SEL(0, h0) SEL(1, h1) SEL(2, h2) SEL(3, h3)
            SEL(4, h4) SEL(5, h5) SEL(6, h6) SEL(7, h7)
#undef SEL
            ov[o] = bv; oi[o] = bi;
            h0 += (bg == 0); h1 += (bg == 1); h2 += (bg == 2); h3 += (bg == 3);
            h4 += (bg == 4); h5 += (bg == 5); h6 += (bg == 6); h7 += (bg == 7);
        }
        float pv[TK];
#pragma unroll
        for (int o = 0; o < TK; ++o) pv[o] = __expf(ov[o] - mstar) / Z;
        float pmax = pv[0];
        float wgt[TK]; float W = 0.0f;
#pragma unroll
        for (int o = 0; o < TK; ++o) { wgt[o] = __expf(pv[o] - pmax); W += wgt[o]; }
#pragma unroll
        for (int o = 0; o < TK; ++o) {
            ldsf[WB_F + p * TK + o] = wgt[o] / W;
            ldsf[IB_F + p * TK + o] = __int_as_float(oi[o]);
        }
    }
    __syncthreads();

    // ---- epilogue: out[:, c, n] = sum_k w_k * mempool[idx_k][c] ----
    {
        const int ep = t & 63, cg = t >> 6;   // 8 c-groups x 64 channels
        float wr[TK]; const float* rows[TK];
#pragma unroll
        for (int o = 0; o < TK; ++o) {
            wr[o]   = ldsf[WB_F + ep * TK + o];
            rows[o] = mp + (size_t)__float_as_int(ldsf[IB_F + ep * TK + o]) * DIMC;
        }
        float* obase = ob + n0 + ep;
#pragma unroll 4
        for (int cc = 0; cc < 16; ++cc) {
            int c = cg * 64 + cc * 4;
            f4 a = {0.0f, 0.0f, 0.0f, 0.0f};
#pragma unroll
            for (int o = 0; o < TK; ++o) {
                f4 rv = *(const f4*)(rows[o] + c);
#pragma unroll
                for (int z = 0; z < 4; ++z) a[z] = fmaf(wr[o], rv[z], a[z]);
            }
#pragma unroll
            for (int z = 0; z < 4; ++z) obase[(size_t)(c + z) * 1024] = a[z];
        }
    }
#undef STAGE_MP
#undef STAGE_Q
}

extern "C" void kernel_launch(void* const* d_in, const int* in_sizes, int n_in,
                              void* d_out, int out_size, void* d_ws, size_t ws_size,
                              hipStream_t stream) {
    const float* x0  = (const float*)d_in[0];
    const float* x1  = (const float*)d_in[1];
    const float* mpl = (const float*)d_in[2];
    float* out = (float*)d_out;
    u16* ws = (u16*)d_ws;

    preconv_kernel<<<dim3(1024), dim3(256), 0, stream>>>(mpl, ws);
    memorize_mfma<<<dim3(512), dim3(TPB), LDS_BYTES, stream>>>(x0, x1, mpl, ws, out);
}

// Round 6
// 660.916 us; speedup vs baseline: 1.4208x; 1.4208x over previous
//
#include <hip/hip_runtime.h>
#include <math.h>

typedef __attribute__((ext_vector_type(4))) float f4;
typedef __attribute__((ext_vector_type(8))) _Float16 f16x8;
typedef __attribute__((ext_vector_type(4))) unsigned short u16x4;
typedef unsigned int u32;
typedef unsigned short u16;

#define DIMC  512
#define NITEM 2048
#define TK    10
#define WSP   (NITEM * DIMC)        // ws plane stride (u16 elems)

// ---------------- main kernel geometry ----------------
#define TPB    512                  // 8 waves
#define PXB    64                   // pixels per block
#define RIT    256                  // items per round
#define NRND   8
#define NSLICE 16                   // K-slices of 32 (K=512)
#define SCL    4.8828125e-4f        // 2^-11 (residual-plane scale)

// ---------------- LDS layout (bytes) ----------------
//   staging: mp planes [2][256 items][64B k-slice] at [0, 32768)
//            q planes  [2][64 px][64B]             at [32768, 40960)
//   S overlay [256][66] f32 at 0..67583 — overlays ALL staging; safe because
//   every staging write happens after the post-scan barrier and every S read
//   happens before it (phase-separated within each round).
//   merge arrays overlay S low region after the last scan.
#define MP_B   0
#define MP_PL  16384
#define Q_B    32768
#define Q_PL   4096
#define SSTR   66
#define LDS_BYTES 67584  // 66 KB -> 2 blocks/CU
// merge overlay (float indices from base 0)
#define MV_F 0        // [64][8][10] vals
#define MI_F 5120     // [64][8][10] idx
#define MM_F 10240    // [64][8] max
#define MS_F 10752    // [64][8] sum
#define WB_F 11264    // [64][10] weights
#define IB_F 11904    // [64][10] indices

// bank-spread swizzle key for 16-row fragment tiles (2-way residual = free)
#define KSWZ(i) (((i) ^ ((i) >> 2)) & 3)

union h16 { _Float16 h; u16 u; };

// fp16 dual-plane split: f ~= lo + 2^-11 * hi  (hi = fp16((f-lo)*2^11))
__device__ __forceinline__ void split2(float f, u16& lo, u16& hi) {
    h16 a; a.h = (_Float16)f;
    float f0 = (float)a.h;
    h16 b; b.h = (_Float16)((f - f0) * 2048.0f);
    lo = a.u; hi = b.u;
}

// mempool fp32 -> 2 fp16 planes in ws, k stored in MFMA fragment permutation:
// within each 32-k slice, position = ((kl>>2)&3)*8 + (kl>>4)*4 + (kl&3)
// (identical perm for A and B -> correctness-invariant to HW k-grouping).
__global__ __launch_bounds__(256)
void preconv_kernel(const float* __restrict__ mp, u16* __restrict__ ws)
{
    int idx = (blockIdx.x * 256 + threadIdx.x) * 4;   // 1024 blocks -> exact
    int i  = idx >> 9;
    int k0 = idx & 511;
    f4 v = *(const f4*)(mp + (size_t)i * 512 + k0);
    int s  = k0 >> 5, kl = k0 & 31;
    int pos = s * 32 + ((kl >> 2) & 3) * 8 + (kl >> 4) * 4;  // + e (e=0..3)
    u16x4 p0, p1;
#pragma unroll
    for (int e = 0; e < 4; ++e) {
        u16 lo, hi; split2(v[e], lo, hi);
        p0[e] = lo; p1[e] = hi;
    }
    size_t base = (size_t)i * 512 + pos;
    *(u16x4*)(ws + 0 * WSP + base) = p0;
    *(u16x4*)(ws + 1 * WSP + base) = p1;
}

__global__ __launch_bounds__(TPB, 4)
void memorize_mfma(const float* __restrict__ x0, const float* __restrict__ x1,
                   const float* __restrict__ mp, const u16* __restrict__ ws,
                   float* __restrict__ out)
{
    extern __shared__ char ldsb[];
    float* ldsf = (float*)ldsb;

    const int t    = threadIdx.x;
    const int lane = t & 63;
    const int w    = t >> 6;            // wave 0..7
    const int blk  = blockIdx.x;        // 0..511
    const int img  = blk >> 4;          // 0..31
    const int n0   = (blk & 15) * PXB;  // pixel base (HW = 1024)
    const int b    = img & 15;

    const float* x  = (img < 16) ? x0 : x1;
    const float* xb = x + (size_t)b * (DIMC * 1024);
    float* ob = out + (img < 16 ? (size_t)0 : (size_t)16 * DIMC * 1024)
                    + (size_t)b * (DIMC * 1024);

    const int l15 = lane & 15;
    const int lh  = lane >> 4;          // fragment h-group 0..3
    const int ksw = lh ^ KSWZ(l15);     // swizzled 16B slot for frag reads

    // scan mapping: 8 groups of 32 items per round per pixel
    const int qp = t & 63;
    const int g  = t >> 6;

    float tv[TK]; int tix[TK];
#pragma unroll
    for (int q = 0; q < TK; ++q) { tv[q] = -INFINITY; tix[q] = 0x7fffffff; }
    float rm = -INFINITY, rs = 0.0f;

    // q staging mapping: thread -> (k-local scl, 4 px)
    const int scl  = t & 31;
    const int spx  = (t >> 5) << 2;     // 0..60
    const int spos = (((scl >> 2) & 3) << 3) + ((scl >> 4) << 2) + (scl & 3);
    const int sslot = spos >> 3;        // true 16B k-slot of this write
    const int soff  = (spos & 7) << 1;  // byte offset within slot

    // mp staging: per-lane source k-slot pre-swizzle (LDS dest stays linear)
    const int itq = lane >> 2;                 // item-local within 16-group
    const int slo = lane & 3;                  // LDS 16B slot this lane fills
    const int ksrc = slo ^ KSWZ(itq);          // true k-slot to fetch

    // fragment LDS base addresses (swizzled)
    const char* qb = ldsb + Q_B + (l15 << 6) + (ksw << 4);
    const char* ab = ldsb + MP_B + (size_t)((w << 5) + l15) * 64 + (ksw << 4);

#pragma unroll 1
    for (int r = 0; r < NRND; ++r) {
        f4 acc0[2][4], acc1[2][4];
#pragma unroll
        for (int mt = 0; mt < 2; ++mt)
#pragma unroll
            for (int nt = 0; nt < 4; ++nt) {
                acc0[mt][nt] = (f4){0.f, 0.f, 0.f, 0.f};
                acc1[mt][nt] = (f4){0.f, 0.f, 0.f, 0.f};
            }

#pragma unroll 1
        for (int s = 0; s < NSLICE; ++s) {
            __syncthreads();   // prev slice frag reads / prev round scan done

            // ---- issue mp staging first: 4 x global_load_lds(16B) ----
            {
#pragma unroll
                for (int p = 0; p < 2; ++p) {
#pragma unroll
                    for (int qg = 0; qg < 2; ++qg) {
                        int I = (w << 5) + (qg << 4);          // item-local base
                        const u16* src = ws + (size_t)p * WSP
                                       + (size_t)(r * RIT + I + itq) * 512
                                       + (s << 5) + (ksrc << 3);
                        char* dst = ldsb + MP_B + p * MP_PL + I * 64;
                        __builtin_amdgcn_global_load_lds(
                            (const __attribute__((address_space(1))) u32*)src,
                            (__attribute__((address_space(3))) u32*)dst, 16, 0, 0);
                    }
                }
            }

            // ---- stage q slice (every slice; swizzled ds_write) ----
            {
                const float* src = xb + (size_t)((s << 5) + scl) * 1024 + n0 + spx;
                f4 v = *(const f4*)src;
#pragma unroll
                for (int e = 0; e < 4; ++e) {
                    int px = spx + e;
                    u16 lo, hi; split2(v[e], lo, hi);
                    int ro = Q_B + (px << 6) + (((sslot ^ KSWZ(px)) << 4) | soff);
                    *(u16*)(ldsb + ro)        = lo;
                    *(u16*)(ldsb + ro + Q_PL) = hi;
                }
            }
            __syncthreads();

            // ---- MFMA: 8 tiles x 3 split-products ----
            f16x8 bq[4][2];
#pragma unroll
            for (int nt = 0; nt < 4; ++nt)
#pragma unroll
                for (int p = 0; p < 2; ++p)
                    bq[nt][p] = *(const f16x8*)(qb + p * Q_PL + nt * 1024);

#pragma unroll
            for (int mt = 0; mt < 2; ++mt) {
                f16x8 a0 = *(const f16x8*)(ab + 0 * MP_PL + mt * 1024);
                f16x8 a1 = *(const f16x8*)(ab + 1 * MP_PL + mt * 1024);
#pragma unroll
                for (int nt = 0; nt < 4; ++nt) {
                    acc0[mt][nt] = __builtin_amdgcn_mfma_f32_16x16x32_f16(
                        a0, bq[nt][0], acc0[mt][nt], 0, 0, 0);
                    acc1[mt][nt] = __builtin_amdgcn_mfma_f32_16x16x32_f16(
                        a0, bq[nt][1], acc1[mt][nt], 0, 0, 0);
                    acc1[mt][nt] = __builtin_amdgcn_mfma_f32_16x16x32_f16(
                        a1, bq[nt][0], acc1[mt][nt], 0, 0, 0);
                }
            }
        }

        // ---- drain accs to S overlay: row=item-local, col=px ----
        __syncthreads();
#pragma unroll
        for (int mt = 0; mt < 2; ++mt) {
#pragma unroll
            for (int nt = 0; nt < 4; ++nt) {
                int row = (w << 5) + (mt << 4) + (lh << 2);   // + reg
                int col = (nt << 4) + l15;
                float* sp = ldsf + row * SSTR + col;
                sp[0 * SSTR] = acc0[mt][nt][0] + SCL * acc1[mt][nt][0];
                sp[1 * SSTR] = acc0[mt][nt][1] + SCL * acc1[mt][nt][1];
                sp[2 * SSTR] = acc0[mt][nt][2] + SCL * acc1[mt][nt][2];
                sp[3 * SSTR] = acc0[mt][nt][3] + SCL * acc1[mt][nt][3];
            }
        }
        __syncthreads();

        // ---- scan sweep 1: max + guarded top-10 insert (32 items/thread) ----
        float mloc = rm;
#pragma unroll 4
        for (int jj = 0; jj < 32; ++jj) {
            int   il = (g << 5) + jj;
            float v  = ldsf[il * SSTR + qp];
            mloc = fmaxf(mloc, v);
            if (v > tv[TK - 1]) {
                int   id = r * RIT + il;
                float cv = v; int ci = id;
#pragma unroll
                for (int q = 0; q < TK; ++q) {
                    bool  gt = cv > tv[q];
                    float nv = gt ? tv[q]  : cv;
                    int   ni = gt ? tix[q] : ci;
                    tv[q]  = gt ? cv : tv[q];
                    tix[q] = gt ? ci : tix[q];
                    cv = nv; ci = ni;
                }
            }
        }
        rs *= __expf(rm - mloc);   // round 0: rs==0 -> ok
        rm = mloc;
        // ---- scan sweep 2: exp-sum at fixed max ----
#pragma unroll 4
        for (int jj = 0; jj < 32; ++jj) {
            int   il = (g << 5) + jj;
            float v  = ldsf[il * SSTR + qp];
            rs += __expf(v - rm);
        }
    }

    // ---- dump per-thread partials for merge ----
    __syncthreads();
    {
#pragma unroll
        for (int q = 0; q < TK; ++q) {
            ldsf[MV_F + (qp * 8 + g) * TK + q] = tv[q];
            ldsf[MI_F + (qp * 8 + g) * TK + q] = __int_as_float(tix[q]);
        }
        ldsf[MM_F + qp * 8 + g] = rm;
        ldsf[MS_F + qp * 8 + g] = rs;
    }
    __syncthreads();

    // ---- merge 8 partial lists per pixel; double softmax ----
    if (t < 64) {
        const int p = t;
        float gm[8], gs[8];
#pragma unroll
        for (int G = 0; G < 8; ++G) {
            gm[G] = ldsf[MM_F + p * 8 + G];
            gs[G] = ldsf[MS_F + p * 8 + G];
        }
        float mstar = gm[0];
#pragma unroll
        for (int G = 1; G < 8; ++G) mstar = fmaxf(mstar, gm[G]);
        float Z = 0.0f;
#pragma unroll
        for (int G = 0; G < 8; ++G) Z += gs[G] * __expf(gm[G] - mstar);

        int h0=0,h1=0,h2=0,h3=0,h4=0,h5=0,h6=0,h7=0;
        float ov[TK]; int oi[TK];
#pragma unroll
        for (int o = 0; o < TK; ++o) {
            float bv = -INFINITY; int bi = 0x7fffffff; int bg = 0;
#define SEL(G, HG)                                                               \
            {                                                                    \
                float v  = ldsf[MV_F + (p * 8 + G) * TK + (HG)];                 \
                int   id = __float_as_int(ldsf[MI_F + (p * 8 + G) * TK + (HG)]); \
                if (v > bv || (v == bv && id < bi)) { bv = v; bi = id; bg = G; } \
            }
            SEL(0, h0) SEL(1, h1) SEL(2, h2) SEL(3, h3)
            SEL(4, h4) SEL(5, h5) SEL(6, h6) SEL(7, h7)
#undef SEL
            ov[o] = bv; oi[o] = bi;
            h0 += (bg == 0); h1 += (bg == 1); h2 += (bg == 2); h3 += (bg == 3);
            h4 += (bg == 4); h5 += (bg == 5); h6 += (bg == 6); h7 += (bg == 7);
        }
        float pv[TK];
#pragma unroll
        for (int o = 0; o < TK; ++o) pv[o] = __expf(ov[o] - mstar) / Z;
        float pmax = pv[0];
        float wgt[TK]; float W = 0.0f;
#pragma unroll
        for (int o = 0; o < TK; ++o) { wgt[o] = __expf(pv[o] - pmax); W += wgt[o]; }
#pragma unroll
        for (int o = 0; o < TK; ++o) {
            ldsf[WB_F + p * TK + o] = wgt[o] / W;
            ldsf[IB_F + p * TK + o] = __int_as_float(oi[o]);
        }
    }
    __syncthreads();

    // ---- epilogue: out[:, c, n] = sum_k w_k * mempool[idx_k][c] ----
    {
        const int ep = t & 63, cg = t >> 6;   // 8 c-groups x 64 channels
        float wr[TK]; const float* rows[TK];
#pragma unroll
        for (int o = 0; o < TK; ++o) {
            wr[o]   = ldsf[WB_F + ep * TK + o];
            rows[o] = mp + (size_t)__float_as_int(ldsf[IB_F + ep * TK + o]) * DIMC;
        }
        float* obase = ob + n0 + ep;
#pragma unroll 4
        for (int cc = 0; cc < 16; ++cc) {
            int c = cg * 64 + cc * 4;
            f4 a = {0.0f, 0.0f, 0.0f, 0.0f};
#pragma unroll
            for (int o = 0; o < TK; ++o) {
                f4 rv = *(const f4*)(rows[o] + c);
#pragma unroll
                for (int z = 0; z < 4; ++z) a[z] = fmaf(wr[o], rv[z], a[z]);
            }
#pragma unroll
            for (int z = 0; z < 4; ++z) obase[(size_t)(c + z) * 1024] = a[z];
        }
    }
}

extern "C" void kernel_launch(void* const* d_in, const int* in_sizes, int n_in,
                              void* d_out, int out_size, void* d_ws, size_t ws_size,
                              hipStream_t stream) {
    const float* x0  = (const float*)d_in[0];
    const float* x1  = (const float*)d_in[1];
    const float* mpl = (const float*)d_in[2];
    float* out = (float*)d_out;
    u16* ws = (u16*)d_ws;

    preconv_kernel<<<dim3(1024), dim3(256), 0, stream>>>(mpl, ws);
    memorize_mfma<<<dim3(512), dim3(TPB), LDS_BYTES, stream>>>(x0, x1, mpl, ws, out);
}

// Round 7
// 558.338 us; speedup vs baseline: 1.6818x; 1.1837x over previous
//
#include <hip/hip_runtime.h>
#include <math.h>

typedef __attribute__((ext_vector_type(4))) float f4;
typedef __attribute__((ext_vector_type(8))) _Float16 f16x8;
typedef __attribute__((ext_vector_type(8))) short bf16x8;
typedef __attribute__((ext_vector_type(4))) unsigned short u16x4;
typedef unsigned int u32;
typedef unsigned short u16;

#define DIMC  512
#define NITEM 2048
#define TK    10
#define WSP   (NITEM * DIMC)        // ws plane stride (u16 elems)

// ---------------- main kernel geometry ----------------
#define TPB    512                  // 8 waves
#define PXB    64                   // pixels per block
#define RIT    256                  // items per round
#define NRND   8
#define NSLICE 16                   // K-slices of 32 (K=512)

// ---------------- LDS layout (bytes) ----------------
//   staging: mp planes [3][256 items][64B k-slice] at [0, 49152)
//            q planes  [3][64 px][64B]             at [49152, 61440)
//   planes: 0 = fp16(x), 1 = bf16(x), 2 = bf16(x - fp16(x))
//   S overlay [256][66] f32 at 0..67583 — overlays ALL staging; phase-
//   separated within each round (staging writes after post-scan barrier,
//   S reads before it).  merge arrays overlay S low region at the end.
#define MP_B   0
#define MP_PL  16384
#define Q_B    49152
#define Q_PL   4096
#define SSTR   66
#define LDS_BYTES 67584  // 66 KB -> 2 blocks/CU
// merge overlay (float indices from base 0)
#define MV_F 0        // [64][8][10] vals
#define MI_F 5120     // [64][8][10] idx
#define MM_F 10240    // [64][8] max
#define MS_F 10752    // [64][8] sum
#define WB_F 11264    // [64][10] weights
#define IB_F 11904    // [64][10] indices

// bank-spread swizzle key for 16-row fragment tiles (2-way residual = free)
#define KSWZ(i) (((i) ^ ((i) >> 2)) & 3)

union h16 { _Float16 h; u16 u; };

__device__ __forceinline__ u32 bf16_rne(float f) {
    u32 u = __float_as_uint(f);
    return (u + 0x7fffu + ((u >> 16) & 1u)) >> 16;
}

// mixed split: f = fp16(f) + residual; planes {fp16(f), bf16(f), bf16(res)}.
// m*q ~= h(m)h(q) + b(m)b(qres) + b(mres)b(q)  (all true-scale -> one acc)
__device__ __forceinline__ void split3(float f, u16& ph, u16& pb, u16& pr) {
    h16 a; a.h = (_Float16)f;
    float f0 = (float)a.h;
    ph = a.u;
    pb = (u16)bf16_rne(f);
    pr = (u16)bf16_rne(f - f0);
}

// mempool fp32 -> 3 planes in ws, k stored in MFMA fragment permutation:
// within each 32-k slice, position = ((kl>>2)&3)*8 + (kl>>4)*4 + (kl&3)
// (identical perm for A and B -> correctness-invariant to HW k-grouping).
__global__ __launch_bounds__(256)
void preconv_kernel(const float* __restrict__ mp, u16* __restrict__ ws)
{
    int idx = (blockIdx.x * 256 + threadIdx.x) * 4;   // 1024 blocks -> exact
    int i  = idx >> 9;
    int k0 = idx & 511;
    f4 v = *(const f4*)(mp + (size_t)i * 512 + k0);
    int s  = k0 >> 5, kl = k0 & 31;
    int pos = s * 32 + ((kl >> 2) & 3) * 8 + (kl >> 4) * 4;  // + e (e=0..3)
    u16x4 pH, pB, pR;
#pragma unroll
    for (int e = 0; e < 4; ++e) {
        u16 h, b, r; split3(v[e], h, b, r);
        pH[e] = h; pB[e] = b; pR[e] = r;
    }
    size_t base = (size_t)i * 512 + pos;
    *(u16x4*)(ws + 0 * WSP + base) = pH;
    *(u16x4*)(ws + 1 * WSP + base) = pB;
    *(u16x4*)(ws + 2 * WSP + base) = pR;
}

__global__ __launch_bounds__(TPB, 4)
void memorize_mfma(const float* __restrict__ x0, const float* __restrict__ x1,
                   const float* __restrict__ mp, const u16* __restrict__ ws,
                   float* __restrict__ out)
{
    extern __shared__ char ldsb[];
    float* ldsf = (float*)ldsb;

    const int t    = threadIdx.x;
    const int lane = t & 63;
    const int w    = t >> 6;            // wave 0..7
    const int blk  = blockIdx.x;        // 0..511
    const int img  = blk >> 4;          // 0..31
    const int n0   = (blk & 15) * PXB;  // pixel base (HW = 1024)
    const int b    = img & 15;

    const float* x  = (img < 16) ? x0 : x1;
    const float* xb = x + (size_t)b * (DIMC * 1024);
    float* ob = out + (img < 16 ? (size_t)0 : (size_t)16 * DIMC * 1024)
                    + (size_t)b * (DIMC * 1024);

    const int l15 = lane & 15;
    const int lh  = lane >> 4;          // fragment h-group 0..3
    const int ksw = lh ^ KSWZ(l15);     // swizzled 16B slot for frag reads

    // scan mapping: 8 groups of 32 items per round per pixel
    const int qp = t & 63;
    const int g  = t >> 6;

    float tv[TK]; int tix[TK];
#pragma unroll
    for (int q = 0; q < TK; ++q) { tv[q] = -INFINITY; tix[q] = 0x7fffffff; }
    float rm = -INFINITY, rs = 0.0f;

    // q staging mapping: thread -> (k-local scl, 4 px)
    const int scl  = t & 31;
    const int spx  = (t >> 5) << 2;     // 0..60
    const int spos = (((scl >> 2) & 3) << 3) + ((scl >> 4) << 2) + (scl & 3);
    const int sslot = spos >> 3;        // true 16B k-slot of this write
    const int soff  = (spos & 7) << 1;  // byte offset within slot

    // mp staging: per-lane source k-slot pre-swizzle (LDS dest stays linear)
    const int itq = lane >> 2;                 // item-local within 16-group
    const int slo = lane & 3;                  // LDS 16B slot this lane fills
    const int ksrc = slo ^ KSWZ(itq);          // true k-slot to fetch

    // fragment LDS base addresses (swizzled)
    const char* qb = ldsb + Q_B + (l15 << 6) + (ksw << 4);
    const char* ab = ldsb + MP_B + (size_t)((w << 5) + l15) * 64 + (ksw << 4);

#pragma unroll 1
    for (int r = 0; r < NRND; ++r) {
        f4 acc[2][4];
#pragma unroll
        for (int mt = 0; mt < 2; ++mt)
#pragma unroll
            for (int nt = 0; nt < 4; ++nt) acc[mt][nt] = (f4){0.f, 0.f, 0.f, 0.f};

#pragma unroll 1
        for (int s = 0; s < NSLICE; ++s) {
            __syncthreads();   // prev slice frag reads / prev round scan done

            // ---- issue mp staging first: 6 x global_load_lds(16B) ----
            {
#pragma unroll
                for (int p = 0; p < 3; ++p) {
#pragma unroll
                    for (int qg = 0; qg < 2; ++qg) {
                        int I = (w << 5) + (qg << 4);          // item-local base
                        const u16* src = ws + (size_t)p * WSP
                                       + (size_t)(r * RIT + I + itq) * 512
                                       + (s << 5) + (ksrc << 3);
                        char* dst = ldsb + MP_B + p * MP_PL + I * 64;
                        __builtin_amdgcn_global_load_lds(
                            (const __attribute__((address_space(1))) u32*)src,
                            (__attribute__((address_space(3))) u32*)dst, 16, 0, 0);
                    }
                }
            }

            // ---- stage q slice (every slice; swizzled ds_write, 3 planes) ----
            {
                const float* src = xb + (size_t)((s << 5) + scl) * 1024 + n0 + spx;
                f4 v = *(const f4*)src;
#pragma unroll
                for (int e = 0; e < 4; ++e) {
                    int px = spx + e;
                    u16 h, bb, rr; split3(v[e], h, bb, rr);
                    int ro = Q_B + (px << 6) + (((sslot ^ KSWZ(px)) << 4) | soff);
                    *(u16*)(ldsb + ro)            = h;
                    *(u16*)(ldsb + ro + Q_PL)     = bb;
                    *(u16*)(ldsb + ro + 2 * Q_PL) = rr;
                }
            }
            __syncthreads();

            // ---- MFMA: 8 tiles x 3 split-products, ONE accumulator bank ----
            f16x8  bqH[4];
            bf16x8 bqB[4], bqR[4];
#pragma unroll
            for (int nt = 0; nt < 4; ++nt) {
                bqH[nt] = *(const f16x8*) (qb + 0 * Q_PL + nt * 1024);
                bqB[nt] = *(const bf16x8*)(qb + 1 * Q_PL + nt * 1024);
                bqR[nt] = *(const bf16x8*)(qb + 2 * Q_PL + nt * 1024);
            }

#pragma unroll
            for (int mt = 0; mt < 2; ++mt) {
                f16x8  aH = *(const f16x8*) (ab + 0 * MP_PL + mt * 1024);
                bf16x8 aB = *(const bf16x8*)(ab + 1 * MP_PL + mt * 1024);
                bf16x8 aR = *(const bf16x8*)(ab + 2 * MP_PL + mt * 1024);
#pragma unroll
                for (int nt = 0; nt < 4; ++nt) {
                    f4 c = acc[mt][nt];
                    c = __builtin_amdgcn_mfma_f32_16x16x32_f16 (aH, bqH[nt], c, 0, 0, 0);
                    c = __builtin_amdgcn_mfma_f32_16x16x32_bf16(aB, bqR[nt], c, 0, 0, 0);
                    c = __builtin_amdgcn_mfma_f32_16x16x32_bf16(aR, bqB[nt], c, 0, 0, 0);
                    acc[mt][nt] = c;
                }
            }
        }

        // ---- drain accs to S overlay: row=item-local, col=px ----
        __syncthreads();
#pragma unroll
        for (int mt = 0; mt < 2; ++mt) {
#pragma unroll
            for (int nt = 0; nt < 4; ++nt) {
                int row = (w << 5) + (mt << 4) + (lh << 2);   // + reg
                int col = (nt << 4) + l15;
                float* sp = ldsf + row * SSTR + col;
                sp[0 * SSTR] = acc[mt][nt][0];
                sp[1 * SSTR] = acc[mt][nt][1];
                sp[2 * SSTR] = acc[mt][nt][2];
                sp[3 * SSTR] = acc[mt][nt][3];
            }
        }
        __syncthreads();

        // ---- scan sweep 1: max + guarded top-10 insert (32 items/thread) ----
        float mloc = rm;
#pragma unroll 4
        for (int jj = 0; jj < 32; ++jj) {
            int   il = (g << 5) + jj;
            float v  = ldsf[il * SSTR + qp];
            mloc = fmaxf(mloc, v);
            if (v > tv[TK - 1]) {
                int   id = r * RIT + il;
                float cv = v; int ci = id;
#pragma unroll
                for (int q = 0; q < TK; ++q) {
                    bool  gt = cv > tv[q];
                    float nv = gt ? tv[q]  : cv;
                    int   ni = gt ? tix[q] : ci;
                    tv[q]  = gt ? cv : tv[q];
                    tix[q] = gt ? ci : tix[q];
                    cv = nv; ci = ni;
                }
            }
        }
        rs *= __expf(rm - mloc);   // round 0: rs==0 -> ok
        rm = mloc;
        // ---- scan sweep 2: exp-sum at fixed max ----
#pragma unroll 4
        for (int jj = 0; jj < 32; ++jj) {
            int   il = (g << 5) + jj;
            float v  = ldsf[il * SSTR + qp];
            rs += __expf(v - rm);
        }
    }

    // ---- dump per-thread partials for merge ----
    __syncthreads();
    {
#pragma unroll
        for (int q = 0; q < TK; ++q) {
            ldsf[MV_F + (qp * 8 + g) * TK + q] = tv[q];
            ldsf[MI_F + (qp * 8 + g) * TK + q] = __int_as_float(tix[q]);
        }
        ldsf[MM_F + qp * 8 + g] = rm;
        ldsf[MS_F + qp * 8 + g] = rs;
    }
    __syncthreads();

    // ---- merge 8 partial lists per pixel; double softmax ----
    if (t < 64) {
        const int p = t;
        float gm[8], gs[8];
#pragma unroll
        for (int G = 0; G < 8; ++G) {
            gm[G] = ldsf[MM_F + p * 8 + G];
            gs[G] = ldsf[MS_F + p * 8 + G];
        }
        float mstar = gm[0];
#pragma unroll
        for (int G = 1; G < 8; ++G) mstar = fmaxf(mstar, gm[G]);
        float Z = 0.0f;
#pragma unroll
        for (int G = 0; G < 8; ++G) Z += gs[G] * __expf(gm[G] - mstar);

        int h0=0,h1=0,h2=0,h3=0,h4=0,h5=0,h6=0,h7=0;
        float ov[TK]; int oi[TK];
#pragma unroll
        for (int o = 0; o < TK; ++o) {
            float bv = -INFINITY; int bi = 0x7fffffff; int bg = 0;
#define SEL(G, HG)                                                               \
            {                                                                    \
                float v  = ldsf[MV_F + (p * 8 + G) * TK + (HG)];                 \
                int   id = __float_as_int(ldsf[MI_F + (p * 8 + G) * TK + (HG)]); \
                if (v > bv || (v == bv && id < bi)) { bv = v; bi = id; bg = G; } \
            }
            SEL(0, h0) SEL(1, h1) SEL(2, h2) SEL(3, h3)
            SEL(4, h4) SEL(5, h5) SEL(6, h6) SEL(7, h7)
#undef SEL
            ov[o] = bv; oi[o] = bi;
            h0 += (bg == 0); h1 += (bg == 1); h2 += (bg == 2); h3 += (bg == 3);
            h4 += (bg == 4); h5 += (bg == 5); h6 += (bg == 6); h7 += (bg == 7);
        }
        float pv[TK];
#pragma unroll
        for (int o = 0; o < TK; ++o) pv[o] = __expf(ov[o] - mstar) / Z;
        float pmax = pv[0];
        float wgt[TK]; float W = 0.0f;
#pragma unroll
        for (int o = 0; o < TK; ++o) { wgt[o] = __expf(pv[o] - pmax); W += wgt[o]; }
#pragma unroll
        for (int o = 0; o < TK; ++o) {
            ldsf[WB_F + p * TK + o] = wgt[o] / W;
            ldsf[IB_F + p * TK + o] = __int_as_float(oi[o]);
        }
    }
    __syncthreads();

    // ---- epilogue: out[:, c, n] = sum_k w_k * mempool[idx_k][c] ----
    {
        const int ep = t & 63, cg = t >> 6;   // 8 c-groups x 64 channels
        float wr[TK]; const float* rows[TK];
#pragma unroll
        for (int o = 0; o < TK; ++o) {
            wr[o]   = ldsf[WB_F + ep * TK + o];
            rows[o] = mp + (size_t)__float_as_int(ldsf[IB_F + ep * TK + o]) * DIMC;
        }
        float* obase = ob + n0 + ep;
#pragma unroll 4
        for (int cc = 0; cc < 16; ++cc) {
            int c = cg * 64 + cc * 4;
            f4 a = {0.0f, 0.0f, 0.0f, 0.0f};
#pragma unroll
            for (int o = 0; o < TK; ++o) {
                f4 rv = *(const f4*)(rows[o] + c);
#pragma unroll
                for (int z = 0; z < 4; ++z) a[z] = fmaf(wr[o], rv[z], a[z]);
            }
#pragma unroll
            for (int z = 0; z < 4; ++z) obase[(size_t)(c + z) * 1024] = a[z];
        }
    }
}

extern "C" void kernel_launch(void* const* d_in, const int* in_sizes, int n_in,
                              void* d_out, int out_size, void* d_ws, size_t ws_size,
                              hipStream_t stream) {
    const float* x0  = (const float*)d_in[0];
    const float* x1  = (const float*)d_in[1];
    const float* mpl = (const float*)d_in[2];
    float* out = (float*)d_out;
    u16* ws = (u16*)d_ws;

    preconv_kernel<<<dim3(1024), dim3(256), 0, stream>>>(mpl, ws);
    memorize_mfma<<<dim3(512), dim3(TPB), LDS_BYTES, stream>>>(x0, x1, mpl, ws, out);
}